// Round 3
// baseline (1122.562 us; speedup 1.0000x reference)
//
#include <hip/hip_runtime.h>
#include <stdint.h>
#include <math.h>

// OTLoss: ft(4096x1024), fs(4096x1024) fp32 -> (loss, P[4096x4096], M[4096x4096])
//
//  1) row-normalize ft, fs -> bf16 A, B
//  2) M_raw = A @ B^T via mfma_f32_16x16x32_bf16, 128x128 tiles, BK=64
//     epilogue: atomic sum/sumsq + per-row max
//  3) stats -> mean, inv_std (ddof=1)
//  4) buildK: M_out = (M_raw-mean)*inv_std; K = exp((M_raw-rowmax)*inv_std) fp16
//  5) Sinkhorn P = diag(u) K diag(v); per iter TWO kernels:
//     fused (1024 blocks, 4 rows/strip): v from t_prev (+conv decision from
//       md scalar), row-matvec u, col partials -> part[32][4096] (32 adds/addr)
//     reduce (32 blocks): t = sum_g part, md[it] = max|v_it*t - c| (atomicMax),
//       zero part.  K is read ONCE per iteration (32 MB, LLC-resident).
//     done flag is iteration-stamped (done = it+1) -> race-free freeze; each
//     block writes its own v_frozen slice.
//  6) final: w = RC/(Kv); sinv = 1/(K^T w); P_ij = K_ij*w_i*sinv_j; loss.

#define NN 4096
#define DIM 1024
#define OT_EPS_F 1e-6f
#define RC (1.0f/4096.0f)

typedef __bf16 bf16_t;
typedef _Float16 half_t;
typedef __bf16 bf16x8 __attribute__((ext_vector_type(8)));
typedef _Float16 halfx8 __attribute__((ext_vector_type(8)));
typedef _Float16 halfx4 __attribute__((ext_vector_type(4)));
typedef float floatx4 __attribute__((ext_vector_type(4)));

typedef __attribute__((address_space(1))) void gv_t;
typedef __attribute__((address_space(3))) void lv_t;

__device__ __forceinline__ uint32_t fkey(float x) {
  uint32_t b = __float_as_uint(x);
  return (b & 0x80000000u) ? ~b : (b | 0x80000000u);
}
__device__ __forceinline__ float funkey(uint32_t k) {
  uint32_t b = (k & 0x80000000u) ? (k & 0x7fffffffu) : ~k;
  return __uint_as_float(b);
}

__device__ __forceinline__ void gld_lds16(const void* g, void* lds_uniform) {
  uint32_t loff = (uint32_t)(uintptr_t)lds_uniform;
  loff = (uint32_t)__builtin_amdgcn_readfirstlane((int)loff);
  __builtin_amdgcn_global_load_lds((gv_t*)(uintptr_t)g, (lv_t*)(uintptr_t)loff, 16, 0, 0);
}

// ws float layout (at fbase)
#define OFF_PART   0         // 32*4096
#define OFF_T      131072    // 3*4096
#define OFF_VF     143360    // 4096
#define OFF_U      147456    // 4096
#define OFF_SINV   151552    // 4096
#define OFF_MD     155648    // 64 (uint bits of nonneg float)
#define OFF_SCAL   155712    // 8: sum,sumsq,mean,inv_std,lossAcc,done
#define OFF_RMAX   155720    // 4096 (uint keys)
#define N_ZERO     159816

// ---------------- init: zero everything ----------------
__global__ void init_ws(float* fbase) {
  int i = blockIdx.x * 256 + threadIdx.x;
  if (i < N_ZERO) ((uint32_t*)fbase)[i] = 0u;
}

// ---------------- row normalize + bf16 cast ----------------
__global__ __launch_bounds__(256) void norm_rows2(const float* __restrict__ ft,
                                                  const float* __restrict__ fs,
                                                  bf16_t* __restrict__ A,
                                                  bf16_t* __restrict__ B) {
  int bid = blockIdx.x;
  const float* X = (bid < 1024) ? ft : fs;
  bf16_t* Y = (bid < 1024) ? A : B;
  int tid = threadIdx.x;
  int wave = tid >> 6, lane = tid & 63;
  int row = (bid & 1023) * 4 + wave;
  const float* xr = X + (size_t)row * DIM;
  float xv[16];
  float ss = 0.f;
#pragma unroll
  for (int k = 0; k < 16; k++) { xv[k] = xr[lane + 64 * k]; ss += xv[k] * xv[k]; }
#pragma unroll
  for (int off = 1; off < 64; off <<= 1) ss += __shfl_xor(ss, off, 64);
  float inv = rsqrtf(ss);
  bf16_t* yr = Y + (size_t)row * DIM;
#pragma unroll
  for (int k = 0; k < 16; k++) yr[lane + 64 * k] = (bf16_t)(xv[k] * inv);
}

// ---------------- GEMM: C = A @ B^T, BK=64, XOR-swizzled LDS ----------------
__global__ __launch_bounds__(256) void gemm_bt(const bf16_t* __restrict__ A,
                                               const bf16_t* __restrict__ B,
                                               float* __restrict__ C,
                                               float* __restrict__ scal,
                                               uint32_t* __restrict__ rowmaxKey) {
  __shared__ __align__(16) bf16_t As[128 * 64];
  __shared__ __align__(16) bf16_t Bs[128 * 64];
  int tid = threadIdx.x;
  int wave = tid >> 6, lane = tid & 63;
  int quad = lane >> 4, l16 = lane & 15;
  int bm = blockIdx.y, bn = blockIdx.x;
  int waveM = wave >> 1, waveN = wave & 1;
  floatx4 acc[4][4] = {};

  for (int k0 = 0; k0 < DIM; k0 += 64) {
#pragma unroll
    for (int t = 0; t < 4; t++) {
      int cbase = t * 256 + wave * 64;
      int c = cbase + lane;
      int row = c >> 3, kcs = c & 7;
      int kc = kcs ^ (row & 7);
      gld_lds16(A + (size_t)(bm * 128 + row) * DIM + (k0 + kc * 8), (char*)As + (size_t)cbase * 16);
      gld_lds16(B + (size_t)(bn * 128 + row) * DIM + (k0 + kc * 8), (char*)Bs + (size_t)cbase * 16);
    }
    __syncthreads();
#pragma unroll
    for (int s = 0; s < 2; s++) {
      bf16x8 af[4], bfr[4];
#pragma unroll
      for (int mt = 0; mt < 4; mt++) {
        int row = waveM * 64 + mt * 16 + l16;
        int kcs = (s * 4 + quad) ^ (l16 & 7);
        af[mt] = *(const bf16x8*)(As + row * 64 + kcs * 8);
      }
#pragma unroll
      for (int nt = 0; nt < 4; nt++) {
        int row = waveN * 64 + nt * 16 + l16;
        int kcs = (s * 4 + quad) ^ (l16 & 7);
        bfr[nt] = *(const bf16x8*)(Bs + row * 64 + kcs * 8);
      }
#pragma unroll
      for (int mt = 0; mt < 4; mt++)
#pragma unroll
        for (int nt = 0; nt < 4; nt++)
          acc[mt][nt] = __builtin_amdgcn_mfma_f32_16x16x32_bf16(af[mt], bfr[nt], acc[mt][nt], 0, 0, 0);
    }
    __syncthreads();
  }

  // C/D layout (m89-verified): col = lane&15, row = quad*4 + reg
  float lsum = 0.f, lsq = 0.f;
#pragma unroll
  for (int mt = 0; mt < 4; mt++) {
#pragma unroll
    for (int r = 0; r < 4; r++) {
      int gi = bm * 128 + waveM * 64 + mt * 16 + quad * 4 + r;
      float rmax = -3.4e38f;
#pragma unroll
      for (int nt = 0; nt < 4; nt++) {
        float vv = acc[mt][nt][r];
        int gj = bn * 128 + waveN * 64 + nt * 16 + l16;
        C[(size_t)gi * NN + gj] = vv;
        lsum += vv;
        lsq += vv * vv;
        rmax = fmaxf(rmax, vv);
      }
#pragma unroll
      for (int off = 1; off < 16; off <<= 1) rmax = fmaxf(rmax, __shfl_xor(rmax, off, 64));
      if (l16 == 0) atomicMax(rowmaxKey + gi, fkey(rmax));
    }
  }
#pragma unroll
  for (int off = 1; off < 64; off <<= 1) {
    lsum += __shfl_xor(lsum, off, 64);
    lsq += __shfl_xor(lsq, off, 64);
  }
  if (lane == 0) { atomicAdd(&scal[0], lsum); atomicAdd(&scal[1], lsq); }
}

// ---------------- mean / inv_std ----------------
__global__ void stats_kernel(float* scal) {
  double sum = (double)scal[0], sumsq = (double)scal[1];
  double N = (double)NN * (double)NN;
  double mean = sum / N;
  double var = (sumsq - sum * sum / N) / (N - 1.0);  // ddof=1
  scal[2] = (float)mean;
  scal[3] = (float)(1.0 / sqrt(var));
}

// ---------------- standardize M in place + build K fp16 ----------------
__global__ __launch_bounds__(256) void build_k(float* __restrict__ M, half_t* __restrict__ K,
                                               const float* __restrict__ scal,
                                               const uint32_t* __restrict__ rowmaxKey) {
  int row = blockIdx.x;
  float mean = scal[2], inv_std = scal[3];
  float rmaxraw = funkey(rowmaxKey[row]);
  float* mrow = M + (size_t)row * NN;
  half_t* krow = K + (size_t)row * NN;
  for (int j4 = threadIdx.x * 4; j4 < NN; j4 += 1024) {
    float raw[4];
    halfx4 kq;
#pragma unroll
    for (int q = 0; q < 4; q++) {
      raw[q] = mrow[j4 + q];
      mrow[j4 + q] = (raw[q] - mean) * inv_std;
      kq[q] = (half_t)__expf((raw[q] - rmaxraw) * inv_std);
    }
    *(halfx4*)(krow + j4) = kq;
  }
}

// ---------------- fused Sinkhorn pass (one K read per iteration) ----------------
// 1024 blocks x 256 threads; block b owns rows [4b,4b+4) and part group b>>5.
// it in [0,20]; it==20 is the final pass (w = u_out, partials -> s).
__global__ __launch_bounds__(256, 4) void sinkhorn_pass(
    const half_t* __restrict__ Km, float* __restrict__ fbase, int it) {
  float* part = fbase + OFF_PART;
  float* tb0 = fbase + OFF_T;
  float* vf = fbase + OFF_VF;
  float* u_out = fbase + OFF_U;
  uint32_t* md = (uint32_t*)(fbase + OFF_MD);
  uint32_t* done = (uint32_t*)(fbase + OFF_SCAL) + 5;

  int tid = threadIdx.x;
  int b = blockIdx.x;
  bool isfinal = (it >= 20);
  uint32_t dn = *done;  // 0, or (freeze_iter+1)
  bool frozen = (dn != 0u && dn <= (uint32_t)it);
  if (frozen && !isfinal) return;

  __shared__ float v_lds[NN];
  __shared__ float u_lds[4];

  int j0 = tid * 16;
  // ---- determine v for this pass ----
  if (isfinal && frozen) {
#pragma unroll
    for (int k = 0; k < 16; k += 4) *(float4*)(v_lds + j0 + k) = *(const float4*)(vf + j0 + k);
  } else if (it == 0) {
#pragma unroll
    for (int k = 0; k < 16; k++) v_lds[j0 + k] = 1.0f;
  } else {
    float mdprev = __uint_as_float(md[it - 1]);
    bool conv = (mdprev <= OT_EPS_F);
    if (conv && !isfinal) {
      // step it-1 converged: freeze v at v_{it-1} = RC/t_{it-2} (ones if it==1)
      if (tid < 4) {
        int j = b * 4 + tid;
        vf[j] = (it == 1) ? 1.0f : RC / tb0[((it - 2) % 3) * NN + j];
      }
      if (tid == 0) *done = (uint32_t)(it);  // stamped: frozen for iters >= it
      return;
    }
    const float* tsrc = conv ? (it == 1 ? nullptr : tb0 + ((it - 2) % 3) * NN)
                             : tb0 + ((it - 1) % 3) * NN;
    if (tsrc == nullptr) {
#pragma unroll
      for (int k = 0; k < 16; k++) v_lds[j0 + k] = 1.0f;
    } else {
#pragma unroll
      for (int k = 0; k < 16; k++) v_lds[j0 + k] = RC / tsrc[j0 + k];
    }
  }
  __syncthreads();

  // ---- row pass: wave w -> row 4b+w: u = RC / sum_j K_ij v_j ----
  int wv = tid >> 6, ln = tid & 63;
  int row = b * 4 + wv;
  {
    const halfx8* kr = (const halfx8*)(Km + (size_t)row * NN);
    const float4* v4 = (const float4*)v_lds;
    float acc = 0.f;
#pragma unroll
    for (int c = 0; c < 8; c++) {
      int idx = c * 64 + ln;
      halfx8 kv = kr[idx];
      float4 va = v4[idx * 2], vb = v4[idx * 2 + 1];
      acc += (float)kv[0] * va.x + (float)kv[1] * va.y + (float)kv[2] * va.z + (float)kv[3] * va.w +
             (float)kv[4] * vb.x + (float)kv[5] * vb.y + (float)kv[6] * vb.z + (float)kv[7] * vb.w;
    }
#pragma unroll
    for (int off = 1; off < 64; off <<= 1) acc += __shfl_xor(acc, off, 64);
    if (ln == 0) {
      float uu = RC / acc;
      u_lds[wv] = uu;
      if (isfinal) u_out[row] = uu;
    }
  }
  __syncthreads();

  // ---- col pass: partials for this strip into part[b>>5][j] ----
  float acc16[16] = {};
  const half_t* kp = Km + (size_t)(b * 4) * NN + j0;
#pragma unroll
  for (int r = 0; r < 4; r++) {
    float ur = u_lds[r];
    halfx8 ka = *(const halfx8*)(kp + (size_t)r * NN);
    halfx8 kb = *(const halfx8*)(kp + (size_t)r * NN + 8);
#pragma unroll
    for (int k = 0; k < 8; k++) {
      acc16[k] += ur * (float)ka[k];
      acc16[k + 8] += ur * (float)kb[k];
    }
  }
  float* prow = part + (size_t)(b >> 5) * NN + j0;
#pragma unroll
  for (int k = 0; k < 16; k++) atomicAdd(prow + k, acc16[k]);
}

// ---------------- reduce partials -> t, convergence max, zero part ----------------
// 32 blocks x 128 threads
__global__ __launch_bounds__(128) void sinkhorn_reduce(float* __restrict__ fbase, int it) {
  float* part = fbase + OFF_PART;
  float* tb0 = fbase + OFF_T;
  float* sinv = fbase + OFF_SINV;
  uint32_t* md = (uint32_t*)(fbase + OFF_MD);
  uint32_t* done = (uint32_t*)(fbase + OFF_SCAL) + 5;

  bool isfinal = (it >= 20);
  uint32_t dn = *done;
  if (!isfinal && dn != 0u && dn <= (uint32_t)it) return;

  int j = blockIdx.x * 128 + threadIdx.x;
  float s = 0.f;
#pragma unroll
  for (int g = 0; g < 32; g++) {
    s += part[(size_t)g * NN + j];
    part[(size_t)g * NN + j] = 0.f;
  }
  if (isfinal) {
    sinv[j] = 1.0f / s;
    return;
  }
  tb0[(it % 3) * NN + j] = s;
  // md[it] = max_j |v_it_j * t_j - RC|, v_it = RC/t_{it-1} (ones at it=0)
  float vit = (it == 0) ? 1.0f : RC / tb0[((it - 1) % 3) * NN + j];
  float d = fabsf(vit * s - RC);
#pragma unroll
  for (int off = 1; off < 64; off <<= 1) d = fmaxf(d, __shfl_xor(d, off, 64));
  if ((threadIdx.x & 63) == 0) atomicMax(md + it, __float_as_uint(d));  // d >= 0: bit-monotone
}

// ---------------- final P write + loss ----------------
__global__ __launch_bounds__(256) void write_p(const half_t* __restrict__ K,
                                               const float* __restrict__ fbase,
                                               float* __restrict__ P,
                                               float* __restrict__ lossAcc) {
  const float* w = fbase + OFF_U;
  const float* sinv = fbase + OFF_SINV;
  int row = blockIdx.x;
  float wi = w[row];
  const half_t* kr = K + (size_t)row * NN;
  float* pr = P + (size_t)row * NN;  // d_out+1 base: 4B-aligned only, scalar stores
  float ls = 0.f;
  for (int j = threadIdx.x; j < NN; j += 256) {
    float p = (float)kr[j] * wi * sinv[j];
    pr[j] = p;
    float d = p - ((j == row) ? 1.0f : 0.0f);
    ls += d * d;
  }
#pragma unroll
  for (int off = 1; off < 64; off <<= 1) ls += __shfl_xor(ls, off, 64);
  __shared__ float r4[4];
  int wave = threadIdx.x >> 6, lane = threadIdx.x & 63;
  if (lane == 0) r4[wave] = ls;
  __syncthreads();
  if (threadIdx.x == 0) atomicAdd(lossAcc, r4[0] + r4[1] + r4[2] + r4[3]);
}

__global__ void final_loss(float* out, const float* lossAcc) { out[0] = sqrtf(*lossAcc); }

// ---------------- launch ----------------
extern "C" void kernel_launch(void* const* d_in, const int* in_sizes, int n_in, void* d_out,
                              int out_size, void* d_ws, size_t ws_size, hipStream_t stream) {
  const float* ft = (const float*)d_in[0];
  const float* fs = (const float*)d_in[1];
  float* out = (float*)d_out;

  char* ws = (char*)d_ws;
  bf16_t* A = (bf16_t*)ws;                  //  8 MiB
  bf16_t* B = (bf16_t*)(ws + (8u << 20));   //  8 MiB
  half_t* K = (half_t*)(ws + (16u << 20));  // 32 MiB
  float* fbase = (float*)(ws + (48u << 20));
  float* scal = fbase + OFF_SCAL;
  uint32_t* rowmaxKey = (uint32_t*)(fbase + OFF_RMAX);

  float* P_out = out + 1;
  float* M_out = out + 1 + (size_t)NN * NN;  // also scratch for M_raw

  init_ws<<<(N_ZERO + 255) / 256, 256, 0, stream>>>(fbase);
  norm_rows2<<<2048, 256, 0, stream>>>(ft, fs, A, B);
  gemm_bt<<<dim3(32, 32), 256, 0, stream>>>(A, B, M_out, scal, rowmaxKey);
  stats_kernel<<<1, 1, 0, stream>>>(scal);
  build_k<<<NN, 256, 0, stream>>>(M_out, K, scal, rowmaxKey);

  for (int it = 0; it <= 20; it++) {
    sinkhorn_pass<<<1024, 256, 0, stream>>>(K, fbase, it);
    sinkhorn_reduce<<<32, 128, 0, stream>>>(fbase, it);
  }

  write_p<<<NN, 256, 0, stream>>>(K, fbase, P_out, scal + 4);
  final_loss<<<1, 1, 0, stream>>>(out, scal + 4);
}